// Round 6
// baseline (193.824 us; speedup 1.0000x reference)
//
#include <hip/hip_runtime.h>

#define N_IMG    1024
#define N_VIEWS  90
#define CENTER   512
#define NTHREADS 256
#define NWAVES   4
#define NJOBS    16        // 16 jobs of 64x16 per block = 256-row y-quarter
#define BUFW     5120      // 20 KB -> 8 blocks/CU (worst staged job <= 4800 words)

typedef float v2f __attribute__((ext_vector_type(2)));

// x_in =  ca*X + sa*Y + cx,  cx = CENTER*(1 - ca - sa)
// y_in = -sa*X + ca*Y + cy,  cy = CENTER*(1 - ca + sa)
// Fixed fmaf chain; samples use the SAME chain (outer fma in Y), so corner
// extremes bound every sample tap exactly (fma monotone per argument).
__device__ __forceinline__ void map_coords(float ca, float sa, float cx, float cy,
                                           float Xf, float Yf,
                                           float& x_in, float& y_in) {
    const float fx0 = fmaf(ca, Xf, cx);
    const float fy0 = fmaf(-sa, Xf, cy);
    x_in = fmaf(sa, Yf, fx0);
    y_in = fmaf(ca, Yf, fy0);
}

// global->LDS DMA: global address PER-LANE, LDS dest = wave-uniform base +
// lane*4. Exec-masked: inactive lanes write nothing (validated R2/R4/R5).
__device__ __forceinline__ void gload_lds4(const float* g, float* l) {
    __builtin_amdgcn_global_load_lds((const __attribute__((address_space(1))) void*)g,
                                     (__attribute__((address_space(3))) void*)l, 4, 0, 0);
}

// One block = (angle, 64-col x-tile, 256-row y-quarter): 16 sequential 64x16
// jobs. Per job: stage exact bbox at pitch P in {32,64,96} (P mod 32 == 0 ->
// bank index depends ONLY on the x-coordinate; per-lane x-stride = ca in
// [-1,1] -> <=2 distinct addresses per bank -> conflict-free reads at every
// angle), sync, sample 4 rows/thread, sync. 8 independent blocks/CU hide
// each other's DMA drains.
__global__ __launch_bounds__(NTHREADS, 8) void radon_q(const float* __restrict__ img,
                                                       const float* __restrict__ theta,
                                                       float* __restrict__ out) {
    __shared__ float buf[BUFW];          // 20 KB exactly

    const int tx = blockIdx.x;
    const int q  = blockIdx.y;
    const int a  = blockIdx.z;
    const int X0 = tx * 64;
    const int Yq = q * (NJOBS * 16);     // 0,256,512,768
    const int tid  = threadIdx.x;
    const int lane = tid & 63;
    const int wv   = tid >> 6;           // 0..3

    // ---- block-uniform per-angle params ----
    const float ang = theta[a] * 0.017453292519943295f;
    float sa, ca;
    __sincosf(ang, &sa, &ca);
    const float cx = (float)CENTER * (1.0f - ca - sa);
    const float cy = (float)CENTER * (1.0f - ca + sa);

    // corner bases (exact, hoisted): x = fma(sa, Y, fx*), y = fma(ca, Y, fy*)
    const float fxA = fmaf(ca, (float)X0,        cx);
    const float fxB = fmaf(ca, (float)(X0 + 63), cx);
    const float fyA = fmaf(-sa, (float)X0,        cy);
    const float fyB = fmaf(-sa, (float)(X0 + 63), cy);

    // ---- per-lane sample-line constants (lane = output column) ----
    const float Xf  = (float)(X0 + lane);
    const float fx0 = fmaf(ca, Xf, cx);
    const float fy0 = fmaf(-sa, Xf, cy);
    const v2f sa2 = {sa, sa};
    const v2f ca2 = {ca, ca};
    const v2f fx2 = {fx0, fx0};
    const v2f fy2 = {fy0, fy0};
    float acc = 0.0f;

    for (int j = 0; j < NJOBS; ++j) {
        // ---- exact job bbox (uniform across threads; same fma chain) ----
        const float Y0f = (float)(Yq + j * 16);
        const float Y1f = Y0f + 15.0f;
        const float x00 = fmaf(sa, Y0f, fxA), x01 = fmaf(sa, Y0f, fxB);
        const float x10 = fmaf(sa, Y1f, fxA), x11 = fmaf(sa, Y1f, fxB);
        const float y00 = fmaf(ca, Y0f, fyA), y01 = fmaf(ca, Y0f, fyB);
        const float y10 = fmaf(ca, Y1f, fyA), y11 = fmaf(ca, Y1f, fyB);
        const float xmin = fminf(fminf(x00, x01), fminf(x10, x11));
        const float xmax = fmaxf(fmaxf(x00, x01), fmaxf(x10, x11));
        const float ymin = fminf(fminf(y00, y01), fminf(y10, y11));
        const float ymax = fmaxf(fmaxf(y00, y01), fmaxf(y10, y11));
        const int ix0 = (int)floorf(xmin);
        const int ix1 = (int)floorf(xmax) + 1;   // rightmost tap (incl. +1)
        const int iy0 = (int)floorf(ymin);
        const int iy1 = (int)floorf(ymax) + 1;   // bottom tap (incl. +1)

        if (ix1 < 0 || ix0 > N_IMG - 1 || iy1 < 0 || iy0 > N_IMG - 1)
            continue;                            // uniform: job fully outside

        const bool interior = (ix0 >= 0) && (ix1 <= N_IMG - 1) &&
                              (iy0 >= 0) && (iy1 <= N_IMG - 1);
        const int win = ix0;                     // exact window start
        const int WS  = ix1 - ix0 + 1;           // staged cols, <= 67
        const int R   = iy1 - iy0 + 1;           // staged rows, <= 67
        const int P   = (WS <= 32) ? 32 : ((WS <= 64) ? 64 : 96);  // == 0 mod 32

        // ---- staging (all DMA writes contiguous -> conflict-free) ----
        if (interior) {
            if (P == 32) {
                // two rows per instruction: lanes 0-31 -> row 2t, 32-63 -> 2t+1
                const int half = lane >> 5, lc = lane & 31;
                const int nt = (R + 1) >> 1;
                for (int t = wv; t < nt; t += NWAVES) {
                    const int r = 2 * t + half;
                    if (lc < WS && r < R)
                        gload_lds4(img + (size_t)(iy0 + r) * N_IMG + win + lc,
                                   buf + (t << 6));
                }
            } else if (P == 64) {
                const float* g = img + (size_t)(iy0 + wv) * N_IMG + win;
                float* l = buf + (wv << 6);
                for (int r = wv; r < R; r += NWAVES) {
                    if (lane < WS) gload_lds4(g + lane, l);
                    g += NWAVES * N_IMG;
                    l += NWAVES * 64;
                }
            } else {
                const float* g = img + (size_t)(iy0 + wv) * N_IMG + win;
                float* l = buf + wv * 96;
                for (int r = wv; r < R; r += NWAVES) {
                    gload_lds4(g + lane, l);
                    if (lane < WS - 64) gload_lds4(g + 64 + lane, l + 64);
                    g += NWAVES * N_IMG;
                    l += NWAVES * 96;
                }
            }
        } else {
            // border: per-lane masked DMA; off-image words -> ds_write 0.
            // cols >= WS stay stale; reads never touch them (taps < WS).
            for (int r = wv; r < R; r += NWAVES) {
                const int gy = iy0 + r;
                const bool rok = ((unsigned)gy < (unsigned)N_IMG);
                const float* gp = img + (size_t)gy * N_IMG;
                float* l = buf + r * P;
                const int gx = win + lane;
                if (lane < WS) {
                    if (rok && (unsigned)gx < (unsigned)N_IMG) gload_lds4(gp + gx, l);
                    else l[lane] = 0.0f;
                }
                if (WS > 64 && lane < WS - 64) {
                    const int gx2 = gx + 64;
                    if (rok && (unsigned)gx2 < (unsigned)N_IMG) gload_lds4(gp + gx2, l + 64);
                    else l[64 + lane] = 0.0f;
                }
            }
        }
        __syncthreads();     // drains this block's DMA; staging visible

        // ---- sample 4 dst rows (wave wv -> rows j*16 + wv*4 ..+4) ----
        // exact coords: x = fma(sa, Y, fx0) per sample (no incremental drift)
        const float Yb = Y0f + (float)(wv << 2);
        const float Pf = (float)P;
        const v2f P2 = {Pf, Pf};
        const float basef = -(float)(iy0 * P + win);
        const v2f b2 = {basef, basef};
        v2f Y2 = {Yb, Yb + 1.0f};
        const v2f two2 = {2.0f, 2.0f};
        v2f acc2 = {0.0f, 0.0f};
        #pragma unroll
        for (int p = 0; p < 2; ++p) {
            const v2f x2 = sa2 * Y2 + fx2;       // v_pk_fma (exact chain)
            const v2f y2 = ca2 * Y2 + fy2;
            v2f x0f = {floorf(x2.x), floorf(x2.y)};
            v2f y0f = {floorf(y2.x), floorf(y2.y)};
            const v2f wx = x2 - x0f;
            const v2f wy = y2 - y0f;
            const v2f lif = y0f * P2 + x0f + b2; // exact (< 2^23)
            const int li0 = (int)lif.x;
            const int li1 = (int)lif.y;
            const int li0p = li0 + P;
            const int li1p = li1 + P;
            const v2f t00 = {buf[li0],      buf[li1]};
            const v2f t01 = {buf[li0 + 1],  buf[li1 + 1]};
            const v2f t10 = {buf[li0p],     buf[li1p]};
            const v2f t11 = {buf[li0p + 1], buf[li1p + 1]};
            const v2f top = (t01 - t00) * wx + t00;
            const v2f bot = (t11 - t10) * wx + t10;
            acc2 += (bot - top) * wy + top;
            Y2 += two2;
        }
        acc += acc2.x + acc2.y;

        __syncthreads();     // all waves done reading before next staging
    }

    // ---- block reduce (overlay buf) + atomic merge of 4 y-quarters ----
    buf[tid] = acc;
    __syncthreads();
    if (tid < 64) {
        const float s = buf[tid] + buf[tid + 64] + buf[tid + 128] + buf[tid + 192];
        atomicAdd(&out[(size_t)(X0 + tid) * N_VIEWS + a], s);
    }
}

extern "C" void kernel_launch(void* const* d_in, const int* in_sizes, int n_in,
                              void* d_out, int out_size, void* d_ws, size_t ws_size,
                              hipStream_t stream) {
    const float* img   = (const float*)d_in[0];   // [1024, 1024] f32
    const float* theta = (const float*)d_in[1];   // [90] f32 degrees
    float* out = (float*)d_out;                   // [1024, 90] f32
    (void)d_ws; (void)ws_size;

    (void)hipMemsetAsync(d_out, 0, (size_t)out_size * sizeof(float), stream);
    radon_q<<<dim3(16, 4, N_VIEWS), NTHREADS, 0, stream>>>(img, theta, out);
}

// Round 8
// 131.823 us; speedup vs baseline: 1.4703x; 1.4703x over previous
//
#include <hip/hip_runtime.h>

#define N_IMG    1024
#define N_VIEWS  90
#define CENTER   512
#define NTHREADS 512
#define NWAVES   8
#define JOBS     4          // 4 jobs of 64x64 per block = 256-row y-quarter
#define PIT      96         // unified LDS pitch; PIT % 32 == 0 -> bank = x0 % 32
#define BUFW     9088       // 92 rows * 96 + 256 (16B-DMA tail overshoot); 35.5 KB -> 4 blk/CU

typedef float v2f __attribute__((ext_vector_type(2)));

// Effective map (post-fold params c,s,cx,cy):
//   x = s*Y + fmaf(c, X, cx),  y = c*Y + fmaf(-s, X, cy)
// Fold (|s0|>|c0|): (c,s,cx,cy,src) <- (s0, -c0, 1023-cy0, cx0, T) with
// T[j][i] = img[1023-i][j]. Identity is EXACT incl. cval=0 borders:
// T_cont(y_T,x_T) = img_cont(1023-x_T, y_T) = img_cont(y_in, x_in).
// Post-fold |c| >= 0.707 for every angle -> one staging/sampling path.
__device__ __forceinline__ void map_coords(float ca, float sa, float cx, float cy,
                                           float Xf, float Yf,
                                           float& x_in, float& y_in) {
    const float fx0 = fmaf(ca, Xf, cx);
    const float fy0 = fmaf(-sa, Xf, cy);
    x_in = fmaf(sa, Yf, fx0);
    y_in = fmaf(ca, Yf, fy0);
}

__device__ __forceinline__ void gload_lds4(const float* g, float* l) {
    __builtin_amdgcn_global_load_lds((const __attribute__((address_space(1))) void*)g,
                                     (__attribute__((address_space(3))) void*)l, 4, 0, 0);
}
__device__ __forceinline__ void gload_lds16(const float* g, float* l) {
    __builtin_amdgcn_global_load_lds((const __attribute__((address_space(1))) void*)g,
                                     (__attribute__((address_space(3))) void*)l, 16, 0, 0);
}

// transposed-flip copy: T[j][i] = img[1023-i][j]; 256 blocks x 256 thr,
// 64x64 tiles via LDS (65 pitch), coalesced on both sides.
__global__ __launch_bounds__(256) void transpose_flip(const float* __restrict__ img,
                                                      float* __restrict__ T) {
    __shared__ float tile[64][65];
    const int t  = blockIdx.x, tr = t >> 4, tc = t & 15;
    const int tid = threadIdx.x, lane = tid & 63, w = tid >> 6;   // 4 waves
    #pragma unroll
    for (int k = 0; k < 16; ++k) {
        const int row = (w << 4) + k;
        tile[row][lane] = img[(size_t)((tr << 6) + row) * N_IMG + (tc << 6) + lane];
    }
    __syncthreads();
    #pragma unroll
    for (int k = 0; k < 16; ++k) {
        const int j = (tc << 6) + (w << 4) + k;       // img col -> T row
        const int i = 1023 - ((tr << 6) + lane);      // img row r -> T col 1023-r
        T[(size_t)j * N_IMG + i] = tile[lane][(w << 4) + k];
    }
}

// One block = (angle, 64-col x-tile, 256-row y-quarter): 4 sequential 64x64
// jobs, R3's verified engine, but single path-0 for ALL angles (fold):
// pitch 96 (bank = x0 mod 32, per-lane stride |c| in [0.707,1] -> <=2-way,
// conflict-free), contiguous 16B DMA interior staging, masked 4B border.
__global__ __launch_bounds__(NTHREADS, 8) void radon_fused(const float* __restrict__ img,
                                                           const float* __restrict__ Tbuf,
                                                           const float* __restrict__ theta,
                                                           float* __restrict__ out,
                                                           int useT) {
    __shared__ float buf[BUFW];          // 35.5 KB -> 4 blocks/CU

    const int tx = blockIdx.x;
    const int q  = blockIdx.y;
    const int a  = blockIdx.z;
    const int X0 = tx * 64;
    const int Yq = q * (JOBS * 64);      // 0,256,512,768
    const int tid  = threadIdx.x;
    const int lane = tid & 63;
    const int wv   = tid >> 6;           // 0..7

    // ---- per-angle params; double sincos once per block (numeric margin) ----
    const float ang = theta[a] * 0.017453292519943295f;
    double sd_, cd_;
    sincos((double)ang, &sd_, &cd_);
    const float s0 = (float)sd_, c0 = (float)cd_;
    const float cx0 = (float)CENTER * (1.0f - c0 - s0);
    const float cy0 = (float)CENTER * (1.0f - c0 + s0);

    float c, s, cx, cy;
    const float* __restrict__ src;
    if (useT && fabsf(s0) > fabsf(c0)) {      // fold steep -> |c| >= 0.707
        c = s0; s = -c0; cx = 1023.0f - cy0; cy = cx0; src = Tbuf;
    } else {
        c = c0; s = s0;  cx = cx0;            cy = cy0;  src = img;
    }

    // ---- per-lane job params: lane (mod 4) owns job jj ----
    const int jj = lane & (JOBS - 1);
    const float Yb = (float)(Yq + jj * 64);
    float x00, y00, x01, y01, x10, y10, x11, y11;
    map_coords(c, s, cx, cy, (float)X0,        Yb,        x00, y00);
    map_coords(c, s, cx, cy, (float)(X0 + 63), Yb,        x01, y01);
    map_coords(c, s, cx, cy, (float)X0,        Yb + 63.f, x10, y10);
    map_coords(c, s, cx, cy, (float)(X0 + 63), Yb + 63.f, x11, y11);
    const float xmin = fminf(fminf(x00, x01), fminf(x10, x11));
    const float xmax = fmaxf(fmaxf(x00, x01), fmaxf(x10, x11));
    const float ymin = fminf(fminf(y00, y01), fminf(y10, y11));
    const float ymax = fmaxf(fmaxf(y00, y01), fmaxf(y10, y11));

    const int ix0 = (int)floorf(xmin);
    const int ix1 = (int)floorf(xmax) + 1;   // rightmost tap; ix1-ix0 <= 91
    const int iy0 = (int)floorf(ymin);
    const int iy1 = (int)floorf(ymax) + 1;   // bottom tap;   iy1-iy0 <= 91

    const bool empty = (ix1 < 0) || (ix0 > N_IMG - 1) ||
                       (iy1 < 0) || (iy0 > N_IMG - 1);
    const bool interior = (ix0 >= 0) && (ix1 <= N_IMG - 1) &&
                          (iy0 >= 0) && (iy1 <= N_IMG - 1);
    // window: 4-aligned, 96 wide, covers [ix0, ix1] (ix1-win <= 91+3 <= 94)
    const int winl = interior ? min(ix0 & ~3, N_IMG - PIT) : (ix0 & ~3);
    const int nrl  = iy1 - iy0 + 1;          // staged rows <= 92
    const int iy0l = iy0;
    const int fll  = empty ? 1 : (interior ? 2 : 0);

    // ---- per-lane sample-line constants (lane = output column) ----
    const float Xf  = (float)(X0 + lane);
    const float bx  = fmaf(c, Xf, cx);       // x = s*Y + bx
    const float by  = fmaf(-s, Xf, cy);      // y = c*Y + by
    const v2f s2 = {s, s}, c2 = {c, c};
    const v2f bx2 = {bx, bx}, by2 = {by, by};
    const v2f P2 = {(float)PIT, (float)PIT};
    float acc = 0.0f;

    for (int j = 0; j < JOBS; ++j) {
        const int win   = __shfl(winl, j);
        const int iyj   = __shfl(iy0l, j);
        const int nrows = __shfl(nrl,  j);
        const int fl    = __shfl(fll,  j);
        if (fl == 1) continue;               // block-uniform: skip empty job

        if (fl & 2) {
            // interior: ONE contiguous region copy (pitch == staged width)
            const int D = nrows * PIT;
            for (int o = wv * 256; o < D; o += NWAVES * 256) {
                const int d = o + 4 * lane;
                const int r = (unsigned)d / 96u;
                const int cc = d - r * 96;
                const int gr = min(iyj + r, N_IMG - 1);   // tail overshoot clamp
                gload_lds16(src + (size_t)gr * N_IMG + win + cc, buf + o);
            }
        } else {
            // border: masked per-lane DMA; off-image words -> ds_write 0
            for (int r = wv; r < nrows; r += NWAVES) {
                const int gy = iyj + r;
                const bool rok = ((unsigned)gy < (unsigned)N_IMG);
                const float* gp = src + (size_t)gy * N_IMG;
                float* l = buf + r * PIT;
                const int gx = win + lane;
                if (rok && (unsigned)gx < (unsigned)N_IMG) gload_lds4(gp + gx, l);
                else l[lane] = 0.0f;
                if (lane < 32) {
                    const int gx2 = gx + 64;
                    if (rok && (unsigned)gx2 < (unsigned)N_IMG) gload_lds4(gp + gx2, l + 64);
                    else l[64 + lane] = 0.0f;
                }
            }
        }
        __syncthreads();     // drains this block's DMA; staging visible

        // ---- sample 8 dst rows (wave wv -> rows j*64 + wv*8 ..+8) ----
        // driftless exact coords (R5-verified): taps stay inside bbox
        const float Yw = (float)(Yq + j * 64 + wv * 8);
        const float basef = -(float)(iyj * PIT + win);
        const v2f b2 = {basef, basef};
        v2f Y2 = {Yw, Yw + 1.0f};
        const v2f two2 = {2.0f, 2.0f};
        v2f acc2 = {0.0f, 0.0f};
        #pragma unroll
        for (int p = 0; p < 4; ++p) {
            const v2f x2 = s2 * Y2 + bx2;    // v_pk_fma (exact chain)
            const v2f y2 = c2 * Y2 + by2;
            const v2f x0f = {floorf(x2.x), floorf(x2.y)};
            const v2f y0f = {floorf(y2.x), floorf(y2.y)};
            const v2f wx = x2 - x0f;
            const v2f wy = y2 - y0f;
            const v2f lif = y0f * P2 + x0f + b2;   // exact (< 2^23)
            const int li0 = (int)lif.x;
            const int li1 = (int)lif.y;
            const v2f t00 = {buf[li0],           buf[li1]};            // ds_read2
            const v2f t01 = {buf[li0 + 1],       buf[li1 + 1]};
            const v2f t10 = {buf[li0 + PIT],     buf[li1 + PIT]};      // ds_read2
            const v2f t11 = {buf[li0 + PIT + 1], buf[li1 + PIT + 1]};
            const v2f top = (t01 - t00) * wx + t00;
            const v2f bot = (t11 - t10) * wx + t10;
            acc2 += (bot - top) * wy + top;
            Y2 += two2;
        }
        acc += acc2.x + acc2.y;

        __syncthreads();     // all waves done reading before next staging
    }

    // ---- block reduce (overlay buf) + atomic merge of 4 y-quarters ----
    buf[wv * 64 + lane] = acc;
    __syncthreads();
    if (wv == 0) {
        float ssum = 0.0f;
        #pragma unroll
        for (int w = 0; w < NWAVES; ++w) ssum += buf[w * 64 + lane];
        atomicAdd(&out[(size_t)(X0 + lane) * N_VIEWS + a], ssum);
    }
}

extern "C" void kernel_launch(void* const* d_in, const int* in_sizes, int n_in,
                              void* d_out, int out_size, void* d_ws, size_t ws_size,
                              hipStream_t stream) {
    const float* img   = (const float*)d_in[0];   // [1024, 1024] f32
    const float* theta = (const float*)d_in[1];   // [90] f32 degrees
    float* out = (float*)d_out;                   // [1024, 90] f32

    float* T = (float*)d_ws;                      // 4 MB transposed-flip copy
    const int useT = (ws_size >= (size_t)N_IMG * N_IMG * sizeof(float)) ? 1 : 0;

    (void)hipMemsetAsync(d_out, 0, (size_t)out_size * sizeof(float), stream);
    if (useT)
        transpose_flip<<<dim3(256), 256, 0, stream>>>(img, T);
    radon_fused<<<dim3(16, 4, N_VIEWS), NTHREADS, 0, stream>>>(img, useT ? T : img,
                                                               theta, out, useT);
}